// Round 3
// baseline (698.838 us; speedup 1.0000x reference)
//
#include <hip/hip_runtime.h>
#include <hip/hip_bf16.h>
#include <stdint.h>

typedef __attribute__((ext_vector_type(8))) short short8;
typedef __attribute__((ext_vector_type(4))) float floatx4;

#define GLOAD_LDS16(gptr, lptr)                                                     \
  __builtin_amdgcn_global_load_lds(                                                 \
      (const __attribute__((address_space(1))) void*)(gptr),                        \
      (__attribute__((address_space(3))) void*)(lptr), 16, 0, 0)

__device__ inline void fwht16(float v[16]) {
#pragma unroll
    for (int s = 0; s < 4; ++s) {
        const int h = 1 << s;
#pragma unroll
        for (int k = 0; k < 16; k += 2 * h)
#pragma unroll
            for (int j = 0; j < h; ++j) {
                float a = v[k + j], b = v[k + j + h];
                v[k + j] = a + b;
                v[k + j + h] = a - b;
            }
    }
}

// ---------------------------------------------------------------------------
// Kernel 1: W_eff[o][i] = Wscale * D4_CB[Qidxs[o][i/4]][i%4] + sum_r A[o][r]*B[r][i]
// A-row reads are wave-uniform -> direct global (s_load), no LDS broadcast.
// grid (16 i-tiles of 256, 64 o-tiles of 64), block 256. FMA-bound.
// ---------------------------------------------------------------------------
__global__ __launch_bounds__(256) void decode_weff(
    const int* __restrict__ Qidxs, const float* __restrict__ D4_CB,
    const float* __restrict__ Wscale_p, const float* __restrict__ A,
    const float* __restrict__ B, __hip_bfloat16* __restrict__ W_eff)
{
    __shared__ __align__(16) float CB[256 * 4];
    const int t = threadIdx.x;
    const int oBase = blockIdx.y * 64;
    const int iBase = blockIdx.x * 256;

    ((float4*)CB)[t] = ((const float4*)D4_CB)[t];
    __syncthreads();

    const float wscale = Wscale_p[0];
    const int i = iBase + t;
    float bcol[64];
#pragma unroll
    for (int r = 0; r < 64; ++r) bcol[r] = B[r * 4096 + i];

    const int g = i >> 2;
    const int sub = i & 3;

    for (int oo = 0; oo < 64; ++oo) {
        const int o = oBase + oo;
        const float4* arow = (const float4*)(A + (long)o * 64);  // uniform -> s_load
        float acc = 0.f;
#pragma unroll
        for (int r4 = 0; r4 < 16; ++r4) {
            float4 a4 = arow[r4];
            acc += a4.x * bcol[4 * r4 + 0] + a4.y * bcol[4 * r4 + 1] +
                   a4.z * bcol[4 * r4 + 2] + a4.w * bcol[4 * r4 + 3];
        }
        const int q = Qidxs[(long)o * 1024 + g];
        const float w = wscale * CB[q * 4 + sub] + acc;
        W_eff[(long)o * 4096 + i] = __float2bfloat16(w);
    }
}

// ---------------------------------------------------------------------------
// Kernels 2/4: FWHT(4096) with phase partition A={0,1,10,11} B={2,3,4,5}
// C={6,7,8,9}. Phase A elements = 4 contiguous float4 quads per thread
// (vectorized global loads). LDS pad pa(e) = e + 4*(e>>6): phase-A b128
// writes conflict-free; B/C b32 accesses 2-way max (free).
// ---------------------------------------------------------------------------
__global__ __launch_bounds__(256) void fwht_in_kernel(
    const float* __restrict__ x, const float* __restrict__ SU,
    const float* __restrict__ sWH, __hip_bfloat16* __restrict__ xh)
{
    __shared__ float row[4096 + 256];
    const int t = threadIdx.x;
    const long base = (long)blockIdx.x * 4096;
    float v[16];

    // phase A: quads q = t + u*256 -> elements e = 4t + j + 1024u
    const float4* xv = (const float4*)(x + base);
    const float4* suv = (const float4*)SU;
    const float4* swv = (const float4*)sWH;
#pragma unroll
    for (int u = 0; u < 4; ++u) {
        const int q = t + u * 256;
        float4 f = xv[q], su = suv[q], sw = swv[q];
        v[u * 4 + 0] = f.x / sw.x * su.x;
        v[u * 4 + 1] = f.y / sw.y * su.y;
        v[u * 4 + 2] = f.z / sw.z * su.z;
        v[u * 4 + 3] = f.w / sw.w * su.w;
    }
    fwht16(v);
    // store: base pa = 4t + 4*(t>>4), u-stride 1088
    {
        float* dst = &row[4 * t + 4 * (t >> 4)];
#pragma unroll
        for (int u = 0; u < 4; ++u) {
            float4 f = make_float4(v[4 * u], v[4 * u + 1], v[4 * u + 2], v[4 * u + 3]);
            *(float4*)(dst + 1088 * u) = f;
        }
    }
    __syncthreads();

    // phase B: bits 2-5. t = hi6*4 + lo2; e = hi6*64 + 4b + lo2; pa = hi6*68 + 4b + lo2
    const int hi6 = t >> 2, lo2 = t & 3;
#pragma unroll
    for (int b = 0; b < 16; ++b) v[b] = row[hi6 * 68 + 4 * b + lo2];
    fwht16(v);
#pragma unroll
    for (int b = 0; b < 16; ++b) row[hi6 * 68 + 4 * b + lo2] = v[b];
    __syncthreads();

    // phase C: bits 6-9. t = hi2*64 + lo6; e = hi2*1024 + 64c + lo6; pa = hi2*1088 + 68c + lo6
    const int hi2 = t >> 6, lo6 = t & 63;
#pragma unroll
    for (int c = 0; c < 16; ++c) v[c] = row[hi2 * 1088 + 68 * c + lo6];
    fwht16(v);

#pragma unroll
    for (int c = 0; c < 16; ++c) {
        __hip_bfloat16 b = __float2bfloat16(v[c] * 0.015625f);
        xh[base + hi2 * 1024 + 64 * c + lo6] = b;   // coalesced across lanes
    }
}

__global__ __launch_bounds__(256) void fwht_out_kernel(
    const __hip_bfloat16* __restrict__ z, const float* __restrict__ SV,
    float* __restrict__ out)
{
    __shared__ float row[4096 + 256];
    const int t = threadIdx.x;
    const long base = (long)blockIdx.x * 4096;
    float v[16];

    // phase A: 4x ushort4 (8B) loads, elements e = 4t + j + 1024u
#pragma unroll
    for (int u = 0; u < 4; ++u) {
        const int q = t + u * 256;
        ushort4 h = *(const ushort4*)(z + base + q * 4);
        union { unsigned int u32; float f32; } c0, c1, c2, c3;
        c0.u32 = (unsigned int)h.x << 16;
        c1.u32 = (unsigned int)h.y << 16;
        c2.u32 = (unsigned int)h.z << 16;
        c3.u32 = (unsigned int)h.w << 16;
        v[u * 4 + 0] = c0.f32;
        v[u * 4 + 1] = c1.f32;
        v[u * 4 + 2] = c2.f32;
        v[u * 4 + 3] = c3.f32;
    }
    fwht16(v);
    {
        float* dst = &row[4 * t + 4 * (t >> 4)];
#pragma unroll
        for (int u = 0; u < 4; ++u) {
            float4 f = make_float4(v[4 * u], v[4 * u + 1], v[4 * u + 2], v[4 * u + 3]);
            *(float4*)(dst + 1088 * u) = f;
        }
    }
    __syncthreads();

    const int hi6 = t >> 2, lo2 = t & 3;
#pragma unroll
    for (int b = 0; b < 16; ++b) v[b] = row[hi6 * 68 + 4 * b + lo2];
    fwht16(v);
#pragma unroll
    for (int b = 0; b < 16; ++b) row[hi6 * 68 + 4 * b + lo2] = v[b];
    __syncthreads();

    const int hi2 = t >> 6, lo6 = t & 63;
#pragma unroll
    for (int c = 0; c < 16; ++c) v[c] = row[hi2 * 1088 + 68 * c + lo6];
    fwht16(v);

#pragma unroll
    for (int c = 0; c < 16; ++c) {
        const int e = hi2 * 1024 + 64 * c + lo6;
        out[base + e] = v[c] * SV[e] * 0.015625f;   // coalesced across lanes
    }
}

// ---------------------------------------------------------------------------
// Kernel 3: z[m][n] = sum_k xh[m][k] * W_eff[n][k]   (bf16 in, bf16 out)
// m97 structure + XOR chunk swizzle (0 bank conflicts, verified r2).
// ---------------------------------------------------------------------------
__global__ __launch_bounds__(256) void gemm_bt(
    const __hip_bfloat16* __restrict__ xh,
    const __hip_bfloat16* __restrict__ wf,
    __hip_bfloat16* __restrict__ z)
{
    __shared__ __align__(16) __hip_bfloat16 lA[128 * 32];
    __shared__ __align__(16) __hip_bfloat16 lB[128 * 32];
    const int t = threadIdx.x;
    const int lane = t & 63;
    const int wv = t >> 6;
    const int wm = (wv >> 1) * 64;
    const int wn = (wv & 1) * 64;
    const long mBase = (long)blockIdx.y * 128;
    const long nBase = (long)blockIdx.x * 128;

    const int srow = wv * 32 + (lane >> 2);
    const int skoff = (((lane & 3) ^ ((lane >> 3) & 3)) * 8);
    const __hip_bfloat16* gA = xh + (mBase + srow) * 4096 + skoff;
    const __hip_bfloat16* gB = wf + (nBase + srow) * 4096 + skoff;
    const long rstep = 16L * 4096;
    __hip_bfloat16* lA0 = &lA[(wv * 32) * 32];
    __hip_bfloat16* lA1 = &lA[(wv * 32 + 16) * 32];
    __hip_bfloat16* lB0 = &lB[(wv * 32) * 32];
    __hip_bfloat16* lB1 = &lB[(wv * 32 + 16) * 32];

    floatx4 acc[4][4] = {};
    const int fr = lane & 15;
    const int q = lane >> 4;
    const int fq = (q ^ ((fr >> 1) & 3)) * 8;

    for (int kt = 0; kt < 4096; kt += 32) {
        GLOAD_LDS16(gA + kt, lA0);
        GLOAD_LDS16(gA + kt + rstep, lA1);
        GLOAD_LDS16(gB + kt, lB0);
        GLOAD_LDS16(gB + kt + rstep, lB1);
        __syncthreads();

        short8 af[4], bfr[4];
#pragma unroll
        for (int i = 0; i < 4; ++i)
            af[i] = *(const short8*)&lA[(wm + i * 16 + fr) * 32 + fq];
#pragma unroll
        for (int j = 0; j < 4; ++j)
            bfr[j] = *(const short8*)&lB[(wn + j * 16 + fr) * 32 + fq];
#pragma unroll
        for (int i = 0; i < 4; ++i)
#pragma unroll
            for (int j = 0; j < 4; ++j)
                acc[i][j] = __builtin_amdgcn_mfma_f32_16x16x32_bf16(
                    af[i], bfr[j], acc[i][j], 0, 0, 0);
        __syncthreads();
    }

    const int q4 = (lane >> 4) * 4;
#pragma unroll
    for (int i = 0; i < 4; ++i)
#pragma unroll
        for (int j = 0; j < 4; ++j)
#pragma unroll
            for (int r = 0; r < 4; ++r) {
                const long rrow = mBase + wm + i * 16 + q4 + r;
                const long ccol = nBase + wn + j * 16 + fr;
                z[rrow * 4096 + ccol] = __float2bfloat16(acc[i][j][r]);
            }
}

// ---------------------------------------------------------------------------
extern "C" void kernel_launch(void* const* d_in, const int* in_sizes, int n_in,
                              void* d_out, int out_size, void* d_ws, size_t ws_size,
                              hipStream_t stream)
{
    const float* input  = (const float*)d_in[0];
    const int*   Qidxs  = (const int*)d_in[1];
    const float* D4_CB  = (const float*)d_in[2];
    const float* SU     = (const float*)d_in[3];
    const float* SV     = (const float*)d_in[4];
    const float* Wscale = (const float*)d_in[5];
    const float* A      = (const float*)d_in[6];
    const float* B      = (const float*)d_in[7];
    const float* sWH    = (const float*)d_in[8];
    float* out = (float*)d_out;

    char* ws = (char*)d_ws;
    __hip_bfloat16* weff = (__hip_bfloat16*)ws;                               // 32 MiB
    __hip_bfloat16* xh   = (__hip_bfloat16*)(ws + (32L << 20));               // 64 MiB
    __hip_bfloat16* zbuf = (__hip_bfloat16*)(ws + (32L << 20) + (64L << 20)); // 64 MiB

    decode_weff<<<dim3(16, 64), 256, 0, stream>>>(Qidxs, D4_CB, Wscale, A, B, weff);
    fwht_in_kernel<<<8192, 256, 0, stream>>>(input, SU, sWH, xh);
    gemm_bt<<<dim3(32, 64), 256, 0, stream>>>(xh, weff, zbuf);
    fwht_out_kernel<<<8192, 256, 0, stream>>>(zbuf, SV, out);
}